// Round 1
// baseline (655.232 us; speedup 1.0000x reference)
//
#include <hip/hip_runtime.h>
#include <hip/hip_bf16.h>

// Problem constants
#define PB   64          // batch
#define PT   100         // time steps
#define PH   128         // height
#define PW   128         // width
#define PF   1024        // pooled features = (128/4)*(128/4)
#define PM   (PB*PT)     // 6400 GEMM rows
#define PK   PF          // 1024
#define PN   200         // neurons
#define BETA1 0.95f
#define BETA2 0.9f

// ---------------- Kernel 1: 4x4 average pooling ----------------
// x: [B,T,128,128] -> xp: [B*T, 1024]  (f = ph*32 + pw)
__global__ __launch_bounds__(256) void pool_kernel(const float* __restrict__ x,
                                                   float* __restrict__ xp) {
    const long total = (long)PM * PF;   // 6,553,600
    for (long idx = (long)blockIdx.x * blockDim.x + threadIdx.x; idx < total;
         idx += (long)gridDim.x * blockDim.x) {
        int f  = (int)(idx & (PF - 1));
        long bt = idx >> 10;
        int ph = f >> 5, pw = f & 31;
        const float* base = x + (bt * PH + ph * 4) * PW + pw * 4;
        float s = 0.0f;
#pragma unroll
        for (int i = 0; i < 4; ++i) {
            float4 v = *reinterpret_cast<const float4*>(base + i * PW);
            s += v.x + v.y + v.z + v.w;
        }
        xp[idx] = s * 0.0625f;
    }
}

// ---------------- Kernel 2: fp32 GEMM g1 = xp * W1^T ----------------
// A: [6400,1024], W1: [200,1024], C: [6400,200]
#define BM 64
#define BN 64
#define BK 64
#define LPAD 4
__global__ __launch_bounds__(256) void gemm_kernel(const float* __restrict__ A,
                                                   const float* __restrict__ W1,
                                                   float* __restrict__ C) {
    __shared__ float Asl[BK][BM + LPAD];
    __shared__ float Wsl[BK][BN + LPAD];
    const int tid = threadIdx.x;
    const int m0 = (blockIdx.x >> 2) * BM;   // 100 m-blocks
    const int n0 = (blockIdx.x & 3) * BN;    // 4 n-blocks (n>=200 masked)
    const int tn = tid & 15;                 // col group
    const int tm = tid >> 4;                 // row group
    const int lr  = tid >> 2;                // staging row 0..63
    const int lc4 = (tid & 3) * 4;           // staging k offset {0,4,8,12}

    float acc[4][4] = {};

    for (int k0 = 0; k0 < PK; k0 += BK) {
        // stage A tile (transpose to k-major)
#pragma unroll
        for (int p = 0; p < 4; ++p) {
            int kk = lc4 + p * 16;
            float4 v = *reinterpret_cast<const float4*>(
                &A[(long)(m0 + lr) * PK + k0 + kk]);
            Asl[kk + 0][lr] = v.x; Asl[kk + 1][lr] = v.y;
            Asl[kk + 2][lr] = v.z; Asl[kk + 3][lr] = v.w;
        }
        // stage W tile (transpose to k-major, mask rows >= 200)
#pragma unroll
        for (int p = 0; p < 4; ++p) {
            int kk = lc4 + p * 16;
            int row = n0 + lr;
            float4 v = make_float4(0.f, 0.f, 0.f, 0.f);
            if (row < PN)
                v = *reinterpret_cast<const float4*>(&W1[(long)row * PK + k0 + kk]);
            Wsl[kk + 0][lr] = v.x; Wsl[kk + 1][lr] = v.y;
            Wsl[kk + 2][lr] = v.z; Wsl[kk + 3][lr] = v.w;
        }
        __syncthreads();
#pragma unroll
        for (int k = 0; k < BK; ++k) {
            float4 av = *reinterpret_cast<const float4*>(&Asl[k][tm * 4]);
            float4 wv = *reinterpret_cast<const float4*>(&Wsl[k][tn * 4]);
            float a_[4] = {av.x, av.y, av.z, av.w};
            float w_[4] = {wv.x, wv.y, wv.z, wv.w};
#pragma unroll
            for (int i = 0; i < 4; ++i)
#pragma unroll
                for (int j = 0; j < 4; ++j)
                    acc[i][j] += a_[i] * w_[j];
        }
        __syncthreads();
    }
    // store (float4 per row; N=200 divisible by 4 so mask is per-quad)
#pragma unroll
    for (int i = 0; i < 4; ++i) {
        int m = m0 + tm * 4 + i;
        int n = n0 + tn * 4;
        if (n < PN) {
            float4 v = make_float4(acc[i][0], acc[i][1], acc[i][2], acc[i][3]);
            *reinterpret_cast<float4*>(&C[(long)m * PN + n]) = v;
        }
    }
}

// ---------------- Kernel 3: LIF scan + W2 + LI scan ----------------
// g1: [B,T,200], W2: [200], y: [B,T]
__global__ __launch_bounds__(256) void scan_kernel(const float* __restrict__ g1,
                                                   const float* __restrict__ W2,
                                                   float* __restrict__ y) {
    __shared__ float part[PT][4];
    const int b = blockIdx.x;
    const int o = threadIdx.x;
    const int wv = o >> 6;
    const int lane = o & 63;
    const float w2 = (o < PN) ? W2[o] : 0.0f;
    float mem = 0.0f;
    const float* gb = g1 + (long)b * PT * PN;

    for (int t = 0; t < PT; ++t) {
        float g = (o < PN) ? gb[t * PN + o] : 0.0f;
        float reset = (mem > 1.0f) ? 1.0f : 0.0f;
        mem = BETA1 * mem + g - reset;           // THR = 1.0
        float c = ((mem - 1.0f) > 0.0f) ? w2 : 0.0f;  // spike * W2[o]
#pragma unroll
        for (int off = 32; off; off >>= 1)
            c += __shfl_xor(c, off, 64);
        if (lane == 0) part[t][wv] = c;
    }
    __syncthreads();
    if (o == 0) {
        float li = 0.0f;
        for (int t = 0; t < PT; ++t) {
            float g2 = part[t][0] + part[t][1] + part[t][2] + part[t][3];
            li = BETA2 * li + g2;               // LI never resets (thr=1e5)
            y[b * PT + t] = li;
        }
    }
}

extern "C" void kernel_launch(void* const* d_in, const int* in_sizes, int n_in,
                              void* d_out, int out_size, void* d_ws, size_t ws_size,
                              hipStream_t stream) {
    const float* x  = (const float*)d_in[0];   // [64,100,128,128]
    const float* W1 = (const float*)d_in[1];   // [200,1024]
    const float* W2 = (const float*)d_in[2];   // [1,200]
    float* y = (float*)d_out;                  // [64,100,1]

    float* xp = (float*)d_ws;                              // 6400*1024 f32 = 26.2 MB
    float* g1 = xp + (long)PM * PF;                        // 6400*200  f32 = 5.1 MB

    pool_kernel<<<2048, 256, 0, stream>>>(x, xp);
    gemm_kernel<<<(PM / BM) * 4, 256, 0, stream>>>(xp, W1, g1);
    scan_kernel<<<PB, 256, 0, stream>>>(g1, W2, y);
}